// Round 13
// baseline (340.538 us; speedup 1.0000x reference)
//
#include <hip/hip_runtime.h>
#include <math.h>

#define NN 80
#define MITERS 50
#define NTHREADS 1024

typedef _Float16 h8 __attribute__((ext_vector_type(8)));
typedef float f4 __attribute__((ext_vector_type(4)));

__device__ __forceinline__ unsigned pk_mul_f16(unsigned a, unsigned b) {
  unsigned d; asm("v_pk_mul_f16 %0, %1, %2" : "=v"(d) : "v"(a), "v"(b)); return d;
}
__device__ __forceinline__ unsigned pk_max_f16(unsigned a, unsigned b) {
  unsigned d; asm("v_pk_max_f16 %0, %1, %2" : "=v"(d) : "v"(a), "v"(b)); return d;
}
__device__ __forceinline__ h8 as_h8(uint4 u) {
  union { uint4 u; h8 h; } x; x.u = u; return x.h;
}
// wave64 sum via DPP (VALU-only, frees the LDS pipe); ctrl must be constexpr
template <int CTRL>
__device__ __forceinline__ float dpp_add(float x) {
  int yi = __builtin_amdgcn_update_dpp(0, __builtin_bit_cast(int, x),
                                       CTRL, 0xf, 0xf, true);
  return x + __builtin_bit_cast(float, yi);
}

// ---- LDS byte offsets (16B-aligned) ----
// XH : fp16 [80][88]  row-major x[i][a], stride 176B
// TT : fp16 [80] rows of 256B, tgt[a][b]; 16B chunk c>>3 at phys
//      (c>>3)^((a>>2)&7)
// MM : 2 bufs fp16 [80 a][104 j], stride 208B, j-block swizzle
//      ^(((a>>2)^(a>>4))&3)   <- round-13 key (breaks ct mod-4 aliasing)
// SRCH: fp16 [80 i][104 j] (0/1), stride 208B, zero pad j>=80
// DL : f32 [80 i][84 a], stride 336B
#define OFF_XH    0
#define OFF_TT    14080
#define OFF_MM    34560
#define OFF_SRCH  67840
#define OFF_DL    84480
#define OFF_FR    111360
#define OFF_FA    111680
#define OFF_RD    112000
#define OFF_AD    112320
#define OFF_WSUM  112640    // 2 x 16 f32, double-buffered
#define OFF_TOT   112768    // 2 f32 (pre-summed norm)
#define OFF_LSUM  112784    // 16 f32
#define LDS_BYTES 112848    // 110.2 KiB < 160 KiB

// Phase-B MFMA C-tile, TRANSPOSED-C form; AF = preloaded A-fragments (uint4[3])
#define DO_TILE_P(I0, A0, XO, AF)                                             \
  {                                                                           \
    const int mk = ((la >> 2) ^ ((A0) >> 4)) & 3;                             \
    f4 acc = {0.f, 0.f, 0.f, 0.f};                                            \
    _Pragma("unroll")                                                         \
    for (int ks = 0; ks < 3; ++ks) {                                          \
      const int mo = ((A0) + la) * 208 + (((ks * 4 + gr) ^ mk) * 16);         \
      const uint4 b0 = *(const uint4*)(MMb + mo);                             \
      const uint4 b1 = *(const uint4*)(MMb + 16640 + mo);                     \
      uint4 bb;                                                               \
      bb.x = pk_max_f16(b0.x, b1.x);                                          \
      bb.y = pk_max_f16(b0.y, b1.y);                                          \
      bb.z = pk_max_f16(b0.z, b1.z);                                          \
      bb.w = pk_max_f16(b0.w, b1.w);                                          \
      acc = __builtin_amdgcn_mfma_f32_16x16x32_f16(as_h8(bb),                 \
                                                   as_h8(AF[ks]), acc,        \
                                                   0, 0, 0);                  \
    }                                                                         \
    const int iN = (I0) + la;                                                 \
    const int ab = (A0) + gr * 4;                                             \
    const float4 dl = *(const float4*)(DLb + iN * 336 + ab * 4);              \
    const float n0 = fmaf(XO[0], dl.x, acc[0]) * inv;                         \
    const float n1 = fmaf(XO[1], dl.y, acc[1]) * inv;                         \
    const float n2 = fmaf(XO[2], dl.z, acc[2]) * inv;                         \
    const float n3 = fmaf(XO[3], dl.w, acc[3]) * inv;                         \
    ss += n0 * n0 + n1 * n1 + n2 * n2 + n3 * n3;                              \
    XO[0] = n0; XO[1] = n1; XO[2] = n2; XO[3] = n3;                           \
    const unsigned ulo = __builtin_bit_cast(                                  \
        unsigned, __builtin_amdgcn_cvt_pkrtz(n0, n1));                        \
    const unsigned uhi = __builtin_bit_cast(                                  \
        unsigned, __builtin_amdgcn_cvt_pkrtz(n2, n3));                        \
    *(uint2*)(XHb + iN * 176 + ab * 2) = make_uint2(ulo, uhi);                \
  }

// variant that re-reads A-fragments from LDS (second tile; saves VGPRs)
#define DO_TILE(I0, A0, XO)                                                   \
  {                                                                           \
    uint4 afr[3];                                                             \
    _Pragma("unroll")                                                         \
    for (int ks = 0; ks < 3; ++ks)                                            \
      afr[ks] =                                                               \
          *(const uint4*)(SRCHb + ((I0) + la) * 208 + ks * 64 + gr * 16);     \
    DO_TILE_P(I0, A0, XO, afr)                                                \
  }

__global__ void __launch_bounds__(NTHREADS, 4)
grf_kernel(const float* __restrict__ recon, const float* __restrict__ adj,
           float* __restrict__ out) {
  extern __shared__ char ldsb[];
  char* XHb = ldsb + OFF_XH;
  char* TTb = ldsb + OFF_TT;
  char* MMb = ldsb + OFF_MM;
  char* SRCHb = ldsb + OFF_SRCH;
  char* DLb = ldsb + OFF_DL;
  float* FR = (float*)(ldsb + OFF_FR);
  float* FA = (float*)(ldsb + OFF_FA);
  float* RD = (float*)(ldsb + OFF_RD);
  float* AD = (float*)(ldsb + OFF_AD);
  float* WSUM = (float*)(ldsb + OFF_WSUM);
  float* TOT = (float*)(ldsb + OFF_TOT);
  float* LSUM = (float*)(ldsb + OFF_LSUM);

  const int t = threadIdx.x;
  const int wave = t >> 6, lane = t & 63;
  const int la = lane & 15, gr = lane >> 4;

  // ---- row sums + diagonals ----
  if (t < 80) {
    float s = 0.f;
    for (int b = 0; b < NN; ++b) s += recon[t * NN + b];
    FR[t] = s;
    RD[t] = recon[t * NN + t];
  } else if (t < 160) {
    const int i = t - 80;
    float s = 0.f;
    for (int j = 0; j < NN; ++j) s += adj[i * NN + j];
    FA[i] = s;
    AD[i] = adj[i * NN + i];
  }
  if (t < 32) {
    const float q = (float)(_Float16)(1.0f / 80.0f);
    WSUM[t] = ((t & 15) == 0) ? 6400.0f * q * q : 0.f;  // ||quantized x0||^2
  }
  __syncthreads();

  // ---- fill operand arrays + BCE loss over triu ----
  float lacc = 0.f;
  for (int f = t; f < NN * NN; f += NTHREADS) {
    const int r = f / NN, c = f - (f / NN) * NN;
    *(_Float16*)(XHb + r * 176 + c * 2) = (_Float16)(1.0f / 80.0f);  // x0[i=r][a=c]
    const float tv = (r == c) ? 0.f : recon[r * NN + c] * RD[r] * RD[c];
    // tgt[a=r][b=c], 8-deep chunk swizzle, 256B row stride
    *(_Float16*)(TTb + r * 256 + (((c >> 3) ^ ((r >> 2) & 7)) * 16) +
                 (c & 7) * 2) = (_Float16)tv;
    *(float*)(DLb + (r * 84 + c) * 4) =
        AD[r] * RD[c] / (fabsf(FA[r] - FR[c]) + 1.f);                // DL[i=r][a=c]
    const float sv = (r == c) ? 0.f : adj[r * NN + c] * AD[r] * AD[c];
    *(_Float16*)(SRCHb + r * 208 + c * 2) = (_Float16)sv;            // SRCH[i=r][j=c]
    if (c >= r) {
      const float tb = adj[f], p = recon[f];
      lacc -= tb * logf(p) + (1.f - tb) * logf(1.f - p);
    }
  }
  // zero pads: SRCH j in [80,104); both MM buffers (8320 u32)
  for (int f = t; f < 1920; f += NTHREADS) {
    const int r = f / 24, j = 80 + (f - (f / 24) * 24);
    *(_Float16*)(SRCHb + r * 208 + j * 2) = (_Float16)0.f;
  }
  for (int f = t; f < 8320; f += NTHREADS) *(unsigned*)(MMb + f * 4) = 0u;

  #pragma unroll
  for (int off = 32; off > 0; off >>= 1) lacc += __shfl_down(lacc, off, 64);
  if (lane == 0) LSUM[wave] = lacc;
  __syncthreads();
  if (t == 0) {
    float s = 0.f;
    for (int w = 0; w < 16; ++w) s += LSUM[w];
    out[0] = s / 3240.f;  // 80*81/2
  }

  // ---- per-wave MFMA tile assignments ----
  const int i00 = (wave / 5) * 16, a00 = (wave % 5) * 16;
  const int tt1 = wave + 16;
  const bool has2 = tt1 < 25;
  const int i01 = has2 ? (tt1 / 5) * 16 : 0;
  const int a01 = has2 ? (tt1 % 5) * 16 : 0;

  // persistent A-fragments for tile 1 (SRCH is static after the sync above)
  uint4 af0[3];
  #pragma unroll
  for (int ks = 0; ks < 3; ++ks)
    af0[ks] = *(const uint4*)(SRCHb + (i00 + la) * 208 + ks * 64 + gr * 16);

  // ---- phase-A mapping: CONTIGUOUS t<800 (balanced across SIMDs:
  // active waves 0..12.5 -> per-SIMD 3.5/3/3/3 instead of 4/4/3.5/1) ----
  const bool actA = (t < 800);
  const int g = (t >= 400) ? 1 : 0;     // b-half
  const int u = t - g * 400;            // 0..399 for active threads
  const int rt = u / 20;                // 0..19 (4-row j-quads)
  const int ct = u - rt * 20;           // 0..19 (4-col a-tiles)
  const char* xrow = XHb + (rt * 4) * 176 + g * 80;   // x rows, b-half g
  const char* trow = TTb + (ct * 4) * 256;            // tgt rows (a)
  const int tkey = ct & 7;              // == ((ct*4+c)>>2)&7 for all c<4
  // MM write base: phys j-block = (rt>>1) ^ ((ct^(ct>>2))&3), 8B half rt&1
  char* mwp = MMb + g * 16640 + (ct * 4) * 208 +
              (((rt >> 1) ^ ((ct ^ (ct >> 2)) & 3)) * 16) + ((rt & 1) * 8);

  // persistent x-old registers for phase B (lane la = i, 4 consecutive a)
  float xo0[4], xo1[4];
  #pragma unroll
  for (int k = 0; k < 4; ++k) xo0[k] = xo1[k] = (float)(_Float16)(1.0f / 80.0f);

  for (int it = 0; it < MITERS; ++it) {
    // ---- Phase A: MM_g[a][j] = max_{b in half} x[j,b]*tgt[a,b] ----
    if (actA) {
      unsigned m[4][4];
      #pragma unroll
      for (int r = 0; r < 4; ++r)
        #pragma unroll
        for (int c = 0; c < 4; ++c) m[r][c] = 0u;
      #pragma unroll
      for (int ch = 0; ch < 5; ++ch) {     // 5 x 8-b chunks in this half
        const uint4 xq0 = *(const uint4*)(xrow + 0 * 176 + ch * 16);
        const uint4 xq1 = *(const uint4*)(xrow + 1 * 176 + ch * 16);
        const uint4 xq2 = *(const uint4*)(xrow + 2 * 176 + ch * 16);
        const uint4 xq3 = *(const uint4*)(xrow + 3 * 176 + ch * 16);
        const int tco = (((g * 5 + ch) ^ tkey) * 16);
        #pragma unroll
        for (int c = 0; c < 4; ++c) {
          const uint4 tq = *(const uint4*)(trow + c * 256 + tco);
          m[0][c] = pk_max_f16(m[0][c], pk_mul_f16(xq0.x, tq.x));
          m[0][c] = pk_max_f16(m[0][c], pk_mul_f16(xq0.y, tq.y));
          m[0][c] = pk_max_f16(m[0][c], pk_mul_f16(xq0.z, tq.z));
          m[0][c] = pk_max_f16(m[0][c], pk_mul_f16(xq0.w, tq.w));
          m[1][c] = pk_max_f16(m[1][c], pk_mul_f16(xq1.x, tq.x));
          m[1][c] = pk_max_f16(m[1][c], pk_mul_f16(xq1.y, tq.y));
          m[1][c] = pk_max_f16(m[1][c], pk_mul_f16(xq1.z, tq.z));
          m[1][c] = pk_max_f16(m[1][c], pk_mul_f16(xq1.w, tq.w));
          m[2][c] = pk_max_f16(m[2][c], pk_mul_f16(xq2.x, tq.x));
          m[2][c] = pk_max_f16(m[2][c], pk_mul_f16(xq2.y, tq.y));
          m[2][c] = pk_max_f16(m[2][c], pk_mul_f16(xq2.z, tq.z));
          m[2][c] = pk_max_f16(m[2][c], pk_mul_f16(xq2.w, tq.w));
          m[3][c] = pk_max_f16(m[3][c], pk_mul_f16(xq3.x, tq.x));
          m[3][c] = pk_max_f16(m[3][c], pk_mul_f16(xq3.y, tq.y));
          m[3][c] = pk_max_f16(m[3][c], pk_mul_f16(xq3.z, tq.z));
          m[3][c] = pk_max_f16(m[3][c], pk_mul_f16(xq3.w, tq.w));
        }
      }
      #pragma unroll
      for (int c = 0; c < 4; ++c) {
        unsigned lo[4];
        #pragma unroll
        for (int r = 0; r < 4; ++r) {
          const unsigned v = m[r][c];
          lo[r] = pk_max_f16(v, (v >> 16) | (v << 16)) & 0xffffu;  // fold b-pair
        }
        *(uint2*)(mwp + c * 208) =
            make_uint2(lo[0] | (lo[1] << 16), lo[2] | (lo[3] << 16));
      }
    } else if (t == 1023) {
      // idle-in-A thread pre-sums the norm partials for this iteration
      const float* W = WSUM + ((it & 1) << 4);
      float s = 0.f;
      #pragma unroll
      for (int w = 0; w < 16; ++w) s += W[w];
      TOT[it & 1] = s;
    }
    __syncthreads();

    // ---- Phase B: x_new = inv * (x*d + SRC @ max(MM0,MM1)), transposed-C ----
    const float inv = 1.0f / sqrtf(TOT[it & 1]);

    float ss = 0.f;
    DO_TILE_P(i00, a00, xo0, af0);
    if (has2) DO_TILE(i01, a01, xo1);

    // wave-64 sum via DPP (VALU-only), total in lane 63
    ss = dpp_add<0x111>(ss);  // row_shr:1
    ss = dpp_add<0x112>(ss);  // row_shr:2
    ss = dpp_add<0x114>(ss);  // row_shr:4
    ss = dpp_add<0x118>(ss);  // row_shr:8
    ss = dpp_add<0x142>(ss);  // row_bcast:15
    ss = dpp_add<0x143>(ss);  // row_bcast:31
    if (lane == 63) WSUM[(((it + 1) & 1) << 4) + wave] = ss;
    __syncthreads();
  }

  // ---- exact final normalization + output (out[1 + i*80 + a]) ----
  {
    const float* WF = WSUM + ((MITERS & 1) << 4);
    float tot = 0.f;
    #pragma unroll
    for (int w = 0; w < 16; ++w) tot += WF[w];
    const float finv = 1.0f / sqrtf(tot);
    for (int f = t; f < NN * NN; f += NTHREADS) {
      const int i = f / NN, a = f - (f / NN) * NN;
      out[1 + f] = (float)*(const _Float16*)(XHb + i * 176 + a * 2) * finv;
    }
  }
}

extern "C" void kernel_launch(void* const* d_in, const int* in_sizes, int n_in,
                              void* d_out, int out_size, void* d_ws, size_t ws_size,
                              hipStream_t stream) {
  const float* recon = (const float*)d_in[0];
  const float* adj   = (const float*)d_in[1];
  float* out = (float*)d_out;
  (void)in_sizes; (void)n_in; (void)out_size; (void)d_ws; (void)ws_size;

  (void)hipFuncSetAttribute(reinterpret_cast<const void*>(grf_kernel),
                            hipFuncAttributeMaxDynamicSharedMemorySize,
                            LDS_BYTES);
  grf_kernel<<<1, NTHREADS, LDS_BYTES, stream>>>(recon, adj, out);
}

// Round 14
// 338.027 us; speedup vs baseline: 1.0074x; 1.0074x over previous
//
#include <hip/hip_runtime.h>
#include <math.h>

#define NN 80
#define MITERS 50
#define NTHREADS 1024

typedef _Float16 h8 __attribute__((ext_vector_type(8)));
typedef float f4 __attribute__((ext_vector_type(4)));

__device__ __forceinline__ unsigned pk_mul_f16(unsigned a, unsigned b) {
  unsigned d; asm("v_pk_mul_f16 %0, %1, %2" : "=v"(d) : "v"(a), "v"(b)); return d;
}
__device__ __forceinline__ unsigned pk_max_f16(unsigned a, unsigned b) {
  unsigned d; asm("v_pk_max_f16 %0, %1, %2" : "=v"(d) : "v"(a), "v"(b)); return d;
}
__device__ __forceinline__ h8 as_h8(uint4 u) {
  union { uint4 u; h8 h; } x; x.u = u; return x.h;
}
// wave64 sum via DPP (VALU-only); ctrl must be constexpr
template <int CTRL>
__device__ __forceinline__ float dpp_add(float x) {
  int yi = __builtin_amdgcn_update_dpp(0, __builtin_bit_cast(int, x),
                                       CTRL, 0xf, 0xf, true);
  return x + __builtin_bit_cast(float, yi);
}

// ---- LDS layout ----
// XH : fp16 [80][88]  row-major x[i][a], stride 176B
// TT : fp16 [80] rows of 256B, tgt[a][b]; 16B chunk c>>3 at phys
//      (c>>3) ^ (((a>>2)*5)&15)   <- r14 key: ct*5 mod 16, max 2-alias (free)
// MM : 2 bufs fp16 [80 a][104 j], stride 208B, j-block swizzle
//      ^(((a>>2)^(a>>4))&3)       <- r13 key (kept; conflicts 126K->113K)
// SRCH: fp16 [80 i][104 j] (0/1), stride 208B, zero pad j>=80
// DL : f32 [80 i][84 a], stride 336B
#define OFF_XH    0
#define OFF_TT    14080
#define OFF_MM    34560
#define OFF_SRCH  67840
#define OFF_DL    84480
#define OFF_FR    111360
#define OFF_FA    111680
#define OFF_RD    112000
#define OFF_AD    112320
#define OFF_WSUM  112640    // 2 x 16 f32, double-buffered
#define OFF_TOT   112768    // 2 f32 (pre-summed norm)
#define OFF_LSUM  112784    // 16 f32
#define LDS_BYTES 112848    // 110.2 KiB < 160 KiB

// Phase-B MFMA C-tile, TRANSPOSED-C form; AF = preloaded A-fragments (uint4[3])
#define DO_TILE_P(I0, A0, XO, AF)                                             \
  {                                                                           \
    const int mk = ((la >> 2) ^ ((A0) >> 4)) & 3;                             \
    f4 acc = {0.f, 0.f, 0.f, 0.f};                                            \
    _Pragma("unroll")                                                         \
    for (int ks = 0; ks < 3; ++ks) {                                          \
      const int mo = ((A0) + la) * 208 + (((ks * 4 + gr) ^ mk) * 16);         \
      const uint4 b0 = *(const uint4*)(MMb + mo);                             \
      const uint4 b1 = *(const uint4*)(MMb + 16640 + mo);                     \
      uint4 bb;                                                               \
      bb.x = pk_max_f16(b0.x, b1.x);                                          \
      bb.y = pk_max_f16(b0.y, b1.y);                                          \
      bb.z = pk_max_f16(b0.z, b1.z);                                          \
      bb.w = pk_max_f16(b0.w, b1.w);                                          \
      acc = __builtin_amdgcn_mfma_f32_16x16x32_f16(as_h8(bb),                 \
                                                   as_h8(AF[ks]), acc,        \
                                                   0, 0, 0);                  \
    }                                                                         \
    const int iN = (I0) + la;                                                 \
    const int ab = (A0) + gr * 4;                                             \
    const float4 dl = *(const float4*)(DLb + iN * 336 + ab * 4);              \
    const float n0 = fmaf(XO[0], dl.x, acc[0]) * inv;                         \
    const float n1 = fmaf(XO[1], dl.y, acc[1]) * inv;                         \
    const float n2 = fmaf(XO[2], dl.z, acc[2]) * inv;                         \
    const float n3 = fmaf(XO[3], dl.w, acc[3]) * inv;                         \
    ss += n0 * n0 + n1 * n1 + n2 * n2 + n3 * n3;                              \
    XO[0] = n0; XO[1] = n1; XO[2] = n2; XO[3] = n3;                           \
    const unsigned ulo = __builtin_bit_cast(                                  \
        unsigned, __builtin_amdgcn_cvt_pkrtz(n0, n1));                        \
    const unsigned uhi = __builtin_bit_cast(                                  \
        unsigned, __builtin_amdgcn_cvt_pkrtz(n2, n3));                        \
    *(uint2*)(XHb + iN * 176 + ab * 2) = make_uint2(ulo, uhi);                \
  }

// variant that re-reads A-fragments from LDS (second tile; saves VGPRs)
#define DO_TILE(I0, A0, XO)                                                   \
  {                                                                           \
    uint4 afr[3];                                                             \
    _Pragma("unroll")                                                         \
    for (int ks = 0; ks < 3; ++ks)                                            \
      afr[ks] =                                                               \
          *(const uint4*)(SRCHb + ((I0) + la) * 208 + ks * 64 + gr * 16);     \
    DO_TILE_P(I0, A0, XO, afr)                                                \
  }

__global__ void __launch_bounds__(NTHREADS, 4)
grf_kernel(const float* __restrict__ recon, const float* __restrict__ adj,
           float* __restrict__ out) {
  extern __shared__ char ldsb[];
  char* XHb = ldsb + OFF_XH;
  char* TTb = ldsb + OFF_TT;
  char* MMb = ldsb + OFF_MM;
  char* SRCHb = ldsb + OFF_SRCH;
  char* DLb = ldsb + OFF_DL;
  float* FR = (float*)(ldsb + OFF_FR);
  float* FA = (float*)(ldsb + OFF_FA);
  float* RD = (float*)(ldsb + OFF_RD);
  float* AD = (float*)(ldsb + OFF_AD);
  float* WSUM = (float*)(ldsb + OFF_WSUM);
  float* TOT = (float*)(ldsb + OFF_TOT);
  float* LSUM = (float*)(ldsb + OFF_LSUM);

  const int t = threadIdx.x;
  const int wave = t >> 6, lane = t & 63;
  const int la = lane & 15, gr = lane >> 4;

  // ---- row sums + diagonals ----
  if (t < 80) {
    float s = 0.f;
    for (int b = 0; b < NN; ++b) s += recon[t * NN + b];
    FR[t] = s;
    RD[t] = recon[t * NN + t];
  } else if (t < 160) {
    const int i = t - 80;
    float s = 0.f;
    for (int j = 0; j < NN; ++j) s += adj[i * NN + j];
    FA[i] = s;
    AD[i] = adj[i * NN + i];
  }
  if (t < 32) {
    const float q = (float)(_Float16)(1.0f / 80.0f);
    WSUM[t] = ((t & 15) == 0) ? 6400.0f * q * q : 0.f;  // ||quantized x0||^2
  }
  __syncthreads();

  // ---- fill operand arrays + BCE loss over triu ----
  float lacc = 0.f;
  for (int f = t; f < NN * NN; f += NTHREADS) {
    const int r = f / NN, c = f - (f / NN) * NN;
    *(_Float16*)(XHb + r * 176 + c * 2) = (_Float16)(1.0f / 80.0f);  // x0[i=r][a=c]
    const float tv = (r == c) ? 0.f : recon[r * NN + c] * RD[r] * RD[c];
    // tgt[a=r][b=c], multiplicative chunk key, 256B row stride
    *(_Float16*)(TTb + r * 256 + (((c >> 3) ^ (((r >> 2) * 5) & 15)) * 16) +
                 (c & 7) * 2) = (_Float16)tv;
    *(float*)(DLb + (r * 84 + c) * 4) =
        AD[r] * RD[c] / (fabsf(FA[r] - FR[c]) + 1.f);                // DL[i=r][a=c]
    const float sv = (r == c) ? 0.f : adj[r * NN + c] * AD[r] * AD[c];
    *(_Float16*)(SRCHb + r * 208 + c * 2) = (_Float16)sv;            // SRCH[i=r][j=c]
    if (c >= r) {
      const float tb = adj[f], p = recon[f];
      lacc -= tb * logf(p) + (1.f - tb) * logf(1.f - p);
    }
  }
  // zero pads: SRCH j in [80,104); both MM buffers (8320 u32)
  for (int f = t; f < 1920; f += NTHREADS) {
    const int r = f / 24, j = 80 + (f - (f / 24) * 24);
    *(_Float16*)(SRCHb + r * 208 + j * 2) = (_Float16)0.f;
  }
  for (int f = t; f < 8320; f += NTHREADS) *(unsigned*)(MMb + f * 4) = 0u;

  #pragma unroll
  for (int off = 32; off > 0; off >>= 1) lacc += __shfl_down(lacc, off, 64);
  if (lane == 0) LSUM[wave] = lacc;
  __syncthreads();
  if (t == 0) {
    float s = 0.f;
    for (int w = 0; w < 16; ++w) s += LSUM[w];
    out[0] = s / 3240.f;  // 80*81/2
  }

  // ---- per-wave MFMA tile assignments ----
  const int i00 = (wave / 5) * 16, a00 = (wave % 5) * 16;
  const int tt1 = wave + 16;
  const bool has2 = tt1 < 25;
  const int i01 = has2 ? (tt1 / 5) * 16 : 0;
  const int a01 = has2 ? (tt1 % 5) * 16 : 0;

  // persistent A-fragments for tile 1 (SRCH is static after the sync above)
  uint4 af0[3];
  #pragma unroll
  for (int ks = 0; ks < 3; ++ks)
    af0[ks] = *(const uint4*)(SRCHb + (i00 + la) * 208 + ks * 64 + gr * 16);

  // ---- phase-A mapping (r12 form): 2 halves x 400 threads, 4x4 tiles ----
  const int g = t >> 9;                 // b-half
  const int u = t & 511;
  const bool actA = (u < 400);
  const int rt = u / 20;                // 0..19 (4-row j-quads)
  const int ct = u - rt * 20;           // 0..19 (4-col a-tiles)
  const char* xrow = XHb + (rt * 4) * 176 + g * 80;   // x rows, b-half g
  const char* trow = TTb + (ct * 4) * 256;            // tgt rows (a)
  const int tkey = (ct * 5) & 15;       // == (((ct*4+c)>>2)*5)&15 for c<4
  // MM write base: phys j-block = (rt>>1) ^ ((ct^(ct>>2))&3), 8B half rt&1
  char* mwp = MMb + g * 16640 + (ct * 4) * 208 +
              (((rt >> 1) ^ ((ct ^ (ct >> 2)) & 3)) * 16) + ((rt & 1) * 8);

  // persistent x-old registers for phase B (lane la = i, 4 consecutive a)
  float xo0[4], xo1[4];
  #pragma unroll
  for (int k = 0; k < 4; ++k) xo0[k] = xo1[k] = (float)(_Float16)(1.0f / 80.0f);

  for (int it = 0; it < MITERS; ++it) {
    // ---- Phase A: MM_g[a][j] = max_{b in half} x[j,b]*tgt[a,b] ----
    if (actA) {
      unsigned m[4][4];
      #pragma unroll
      for (int r = 0; r < 4; ++r)
        #pragma unroll
        for (int c = 0; c < 4; ++c) m[r][c] = 0u;
      #pragma unroll
      for (int ch = 0; ch < 5; ++ch) {     // 5 x 8-b chunks in this half
        const uint4 xq0 = *(const uint4*)(xrow + 0 * 176 + ch * 16);
        const uint4 xq1 = *(const uint4*)(xrow + 1 * 176 + ch * 16);
        const uint4 xq2 = *(const uint4*)(xrow + 2 * 176 + ch * 16);
        const uint4 xq3 = *(const uint4*)(xrow + 3 * 176 + ch * 16);
        const int tco = (((g * 5 + ch) ^ tkey) * 16);
        #pragma unroll
        for (int c = 0; c < 4; ++c) {
          const uint4 tq = *(const uint4*)(trow + c * 256 + tco);
          m[0][c] = pk_max_f16(m[0][c], pk_mul_f16(xq0.x, tq.x));
          m[0][c] = pk_max_f16(m[0][c], pk_mul_f16(xq0.y, tq.y));
          m[0][c] = pk_max_f16(m[0][c], pk_mul_f16(xq0.z, tq.z));
          m[0][c] = pk_max_f16(m[0][c], pk_mul_f16(xq0.w, tq.w));
          m[1][c] = pk_max_f16(m[1][c], pk_mul_f16(xq1.x, tq.x));
          m[1][c] = pk_max_f16(m[1][c], pk_mul_f16(xq1.y, tq.y));
          m[1][c] = pk_max_f16(m[1][c], pk_mul_f16(xq1.z, tq.z));
          m[1][c] = pk_max_f16(m[1][c], pk_mul_f16(xq1.w, tq.w));
          m[2][c] = pk_max_f16(m[2][c], pk_mul_f16(xq2.x, tq.x));
          m[2][c] = pk_max_f16(m[2][c], pk_mul_f16(xq2.y, tq.y));
          m[2][c] = pk_max_f16(m[2][c], pk_mul_f16(xq2.z, tq.z));
          m[2][c] = pk_max_f16(m[2][c], pk_mul_f16(xq2.w, tq.w));
          m[3][c] = pk_max_f16(m[3][c], pk_mul_f16(xq3.x, tq.x));
          m[3][c] = pk_max_f16(m[3][c], pk_mul_f16(xq3.y, tq.y));
          m[3][c] = pk_max_f16(m[3][c], pk_mul_f16(xq3.z, tq.z));
          m[3][c] = pk_max_f16(m[3][c], pk_mul_f16(xq3.w, tq.w));
        }
      }
      #pragma unroll
      for (int c = 0; c < 4; ++c) {
        unsigned lo[4];
        #pragma unroll
        for (int r = 0; r < 4; ++r) {
          const unsigned v = m[r][c];
          lo[r] = pk_max_f16(v, (v >> 16) | (v << 16)) & 0xffffu;  // fold b-pair
        }
        *(uint2*)(mwp + c * 208) =
            make_uint2(lo[0] | (lo[1] << 16), lo[2] | (lo[3] << 16));
      }
    } else if (t == 1023) {
      // idle-in-A thread pre-sums the norm partials for this iteration
      const float* W = WSUM + ((it & 1) << 4);
      float s = 0.f;
      #pragma unroll
      for (int w = 0; w < 16; ++w) s += W[w];
      TOT[it & 1] = s;
    }
    __syncthreads();

    // ---- Phase B: x_new = inv * (x*d + SRC @ max(MM0,MM1)), transposed-C ----
    const float inv = 1.0f / sqrtf(TOT[it & 1]);

    float ss = 0.f;
    DO_TILE_P(i00, a00, xo0, af0);
    if (has2) DO_TILE(i01, a01, xo1);

    // wave-64 sum via DPP (VALU-only), total in lane 63
    ss = dpp_add<0x111>(ss);  // row_shr:1
    ss = dpp_add<0x112>(ss);  // row_shr:2
    ss = dpp_add<0x114>(ss);  // row_shr:4
    ss = dpp_add<0x118>(ss);  // row_shr:8
    ss = dpp_add<0x142>(ss);  // row_bcast:15
    ss = dpp_add<0x143>(ss);  // row_bcast:31
    if (lane == 63) WSUM[(((it + 1) & 1) << 4) + wave] = ss;
    __syncthreads();
  }

  // ---- exact final normalization + output (out[1 + i*80 + a]) ----
  {
    const float* WF = WSUM + ((MITERS & 1) << 4);
    float tot = 0.f;
    #pragma unroll
    for (int w = 0; w < 16; ++w) tot += WF[w];
    const float finv = 1.0f / sqrtf(tot);
    for (int f = t; f < NN * NN; f += NTHREADS) {
      const int i = f / NN, a = f - (f / NN) * NN;
      out[1 + f] = (float)*(const _Float16*)(XHb + i * 176 + a * 2) * finv;
    }
  }
}

extern "C" void kernel_launch(void* const* d_in, const int* in_sizes, int n_in,
                              void* d_out, int out_size, void* d_ws, size_t ws_size,
                              hipStream_t stream) {
  const float* recon = (const float*)d_in[0];
  const float* adj   = (const float*)d_in[1];
  float* out = (float*)d_out;
  (void)in_sizes; (void)n_in; (void)out_size; (void)d_ws; (void)ws_size;

  (void)hipFuncSetAttribute(reinterpret_cast<const void*>(grf_kernel),
                            hipFuncAttributeMaxDynamicSharedMemorySize,
                            LDS_BYTES);
  grf_kernel<<<1, NTHREADS, LDS_BYTES, stream>>>(recon, adj, out);
}